// Round 2
// baseline (439.517 us; speedup 1.0000x reference)
//
#include <hip/hip_runtime.h>

// Problem: SSIM3D loss over 64 independent 64^3 f32 volumes (2*8*4 channels),
// separable 7-tap gaussian (sigma=1.5), edge-replicate padding.
// loss = mean over all voxels of (1 - ssim). (p/s split == global mean.)

#define VOL 64
#define TILE 8
#define RAD 3
#define IW 14              // TILE + 2*RAD
#define IN3 (IW*IW*IW)     // 2744
#define ST1 (IW*IW*TILE)   // 1568
#define ST2 (IW*TILE*TILE) // 896

__global__ void zero_acc_kernel(double* acc) {
    if (threadIdx.x == 0) *acc = 0.0;
}

__global__ void finalize_kernel(const double* __restrict__ acc, float* __restrict__ out) {
    if (threadIdx.x == 0) out[0] = (float)(*acc * (1.0 / 16777216.0));
}

__launch_bounds__(256)
__global__ void ssim3d_kernel(const float* __restrict__ preds,
                              const float* __restrict__ trues,
                              double* __restrict__ acc)
{
    // block -> volume v (64) x tile (8x8x8 tiles of 8^3)
    const int bid = blockIdx.x;
    const int v   = bid >> 9;
    const int t   = bid & 511;
    const int ox  = (t >> 6) * TILE;
    const int oy  = ((t >> 3) & 7) * TILE;
    const int oz  = (t & 7) * TILE;

    const size_t vbase = (size_t)v * (VOL * VOL * VOL);
    const float* __restrict__ xp = preds + vbase;
    const float* __restrict__ yp = trues + vbase;

    // LDS layout (floats):
    //   sx [0      .. 2744)   input x, 14^3
    //   sy [2744   .. 5488)   input y, 14^3
    //   st1[5488   .. 13328)  5 fields x 14*14*8   (after Z pass)
    //   st2 overlays sx/sy: 5 fields x 14*8*8 = 4480 <= 5488
    __shared__ float smem[5488 + 5 * ST1];
    float* sx  = smem;
    float* sy  = smem + IN3;
    float* st1 = smem + 2 * IN3;
    float* st2 = smem;  // valid after Z pass completes

    const float g[7] = {0.03663285f, 0.11128074f, 0.21674532f, 0.27068219f,
                        0.21674532f, 0.11128074f, 0.03663285f};

    // ---- load halo'd 14^3 region, edge-clamped ----
    for (int i = threadIdx.x; i < IN3; i += 256) {
        int iz = i % IW;
        int r  = i / IW;
        int iy = r % IW;
        int ix = r / IW;
        int gx = min(max(ox - RAD + ix, 0), VOL - 1);
        int gy = min(max(oy - RAD + iy, 0), VOL - 1);
        int gz = min(max(oz - RAD + iz, 0), VOL - 1);
        int gi = (gx * VOL + gy) * VOL + gz;
        sx[i] = xp[gi];
        sy[i] = yp[gi];
    }
    __syncthreads();

    // ---- Z pass: (ix,iy in [0,14), z in [0,8)) -> 5 fields ----
    for (int i = threadIdx.x; i < IW * IW * TILE; i += 256) {
        int z  = i & 7;
        int r  = i >> 3;
        int iy = r % IW;
        int ix = r / IW;
        const float* bx = &sx[(ix * IW + iy) * IW + z];
        const float* by = &sy[(ix * IW + iy) * IW + z];
        float m1 = 0.f, m2 = 0.f, e11 = 0.f, e22 = 0.f, e12 = 0.f;
#pragma unroll
        for (int k = 0; k < 7; k++) {
            float a = bx[k], b = by[k], w = g[k];
            m1  += w * a;
            m2  += w * b;
            e11 += w * a * a;
            e22 += w * b * b;
            e12 += w * a * b;
        }
        int o = (ix * IW + iy) * TILE + z;
        st1[o]           = m1;
        st1[ST1 + o]     = m2;
        st1[2 * ST1 + o] = e11;
        st1[3 * ST1 + o] = e22;
        st1[4 * ST1 + o] = e12;
    }
    __syncthreads();  // st1 done; sx/sy dead -> st2 may overlay

    // ---- Y pass: (ix in [0,14), y,z in [0,8)) ----
    for (int i = threadIdx.x; i < IW * TILE * TILE; i += 256) {
        int z  = i & 7;
        int r  = i >> 3;
        int y  = r & 7;
        int ix = r >> 3;
#pragma unroll
        for (int f = 0; f < 5; f++) {
            const float* b = &st1[f * ST1 + (ix * IW + y) * TILE + z];
            float s = 0.f;
#pragma unroll
            for (int k = 0; k < 7; k++) s += g[k] * b[k * TILE];
            st2[f * ST2 + (ix * TILE + y) * TILE + z] = s;
        }
    }
    __syncthreads();

    // ---- X pass + SSIM + local accumulate ----
    const float C1 = 1e-4f, C2 = 9e-4f;
    float lsum = 0.f;
    for (int i = threadIdx.x; i < TILE * TILE * TILE; i += 256) {
        int z = i & 7;
        int r = i >> 3;
        int y = r & 7;
        int x = r >> 3;
        float m1 = 0.f, m2 = 0.f, e11 = 0.f, e22 = 0.f, e12 = 0.f;
#pragma unroll
        for (int k = 0; k < 7; k++) {
            int o = ((x + k) * TILE + y) * TILE + z;
            float w = g[k];
            m1  += w * st2[o];
            m2  += w * st2[ST2 + o];
            e11 += w * st2[2 * ST2 + o];
            e22 += w * st2[3 * ST2 + o];
            e12 += w * st2[4 * ST2 + o];
        }
        float mu1sq = m1 * m1, mu2sq = m2 * m2, mu12 = m1 * m2;
        float s11 = e11 - mu1sq;
        float s22 = e22 - mu2sq;
        float s12 = e12 - mu12;
        float num = (2.f * mu12 + C1) * (2.f * s12 + C2);
        float den = (mu1sq + mu2sq + C1) * (s11 + s22 + C2);
        float ssim = num / (den + 1e-12f);
        lsum += 1.f - ssim;
    }

    // ---- block reduction: wave shuffle then LDS across 4 waves ----
#pragma unroll
    for (int off = 32; off > 0; off >>= 1)
        lsum += __shfl_down(lsum, off);

    __shared__ float wsum[4];
    const int lane = threadIdx.x & 63;
    const int wid  = threadIdx.x >> 6;
    if (lane == 0) wsum[wid] = lsum;
    __syncthreads();
    if (threadIdx.x == 0) {
        float b = wsum[0] + wsum[1] + wsum[2] + wsum[3];
        atomicAdd(acc, (double)b);
    }
}

extern "C" void kernel_launch(void* const* d_in, const int* in_sizes, int n_in,
                              void* d_out, int out_size, void* d_ws, size_t ws_size,
                              hipStream_t stream) {
    const float* preds = (const float*)d_in[0];
    const float* trues = (const float*)d_in[1];
    float* out = (float*)d_out;
    double* acc = (double*)d_ws;

    hipLaunchKernelGGL(zero_acc_kernel, dim3(1), dim3(64), 0, stream, acc);

    const int nblocks = 64 * 512;  // 64 volumes x 8^3 tiles
    hipLaunchKernelGGL(ssim3d_kernel, dim3(nblocks), dim3(256), 0, stream,
                       preds, trues, acc);

    hipLaunchKernelGGL(finalize_kernel, dim3(1), dim3(64), 0, stream, acc, out);
}

// Round 3
// 313.193 us; speedup vs baseline: 1.4033x; 1.4033x over previous
//
#include <hip/hip_runtime.h>

// SSIM3D loss, 64 x (64^3) f32 volumes, separable 7-tap gaussian, edge clamp.
// Structure: block = 16x16 (x,y) output tile x full z=64 streamed in registers.
// z-conv in registers (7-deep raw sliding windows), y/x convs via LDS (SoA by
// field, ds_read_b64 tap-pairs, output-pair tap sharing, symmetric weights).

#define VOL 64
#define VOXPV (VOL*VOL*VOL)
#define TX 16
#define TY 16
#define PX 22
#define PY 22
#define PYS 24            // padded stride for stage arrays
#define NPOS (PX*PY)      // 484
#define S1F (PX*PYS)      // 528 floats per field
#define S2F (TY*PYS)      // 384 floats per field

#define G0 0.03663285f
#define G1 0.11128074f
#define G2 0.21674532f
#define G3 0.27068219f

__global__ void zero_acc_kernel(double* acc) {
    if (threadIdx.x == 0) *acc = 0.0;
}

__global__ void finalize_kernel(const double* __restrict__ acc, float* __restrict__ out) {
    if (threadIdx.x == 0) out[0] = (float)(*acc * (1.0 / 16777216.0));
}

__device__ __forceinline__ float f4c(const float4& v, int ph) {
    return ph == 0 ? v.x : ph == 1 ? v.y : ph == 2 ? v.z : v.w;
}

__device__ __forceinline__ void zconv5(const float a[7], const float b[7], float o[5]) {
    o[0] = G0*(a[0]+a[6]) + G1*(a[1]+a[5]) + G2*(a[2]+a[4]) + G3*a[3];
    o[1] = G0*(b[0]+b[6]) + G1*(b[1]+b[5]) + G2*(b[2]+b[4]) + G3*b[3];
    o[2] = G0*(a[0]*a[0]+a[6]*a[6]) + G1*(a[1]*a[1]+a[5]*a[5])
         + G2*(a[2]*a[2]+a[4]*a[4]) + G3*(a[3]*a[3]);
    o[3] = G0*(b[0]*b[0]+b[6]*b[6]) + G1*(b[1]*b[1]+b[5]*b[5])
         + G2*(b[2]*b[2]+b[4]*b[4]) + G3*(b[3]*b[3]);
    o[4] = G0*(a[0]*b[0]+a[6]*b[6]) + G1*(a[1]*b[1]+a[5]*b[5])
         + G2*(a[2]*b[2]+a[4]*b[4]) + G3*(a[3]*b[3]);
}

__device__ __forceinline__ float ssim_term(const float r[5]) {
    const float C1 = 1e-4f, C2 = 9e-4f;
    float mu1 = r[0], mu2 = r[1];
    float m11 = mu1*mu1, m22 = mu2*mu2, m12 = mu1*mu2;
    float s11 = r[2] - m11, s22 = r[3] - m22, s12 = r[4] - m12;
    float num = (2.f*m12 + C1) * (2.f*s12 + C2);
    float den = (m11 + m22 + C1) * (s11 + s22 + C2);
    return 1.f - num / (den + 1e-12f);
}

__launch_bounds__(256)
__global__ void ssim3d_kernel(const float* __restrict__ preds,
                              const float* __restrict__ trues,
                              double* __restrict__ acc)
{
    const int tid = threadIdx.x;
    const int bid = blockIdx.x;
    const int v   = bid >> 4;
    const int t   = bid & 15;
    const int ox  = (t >> 2) * TX;
    const int oy  = (t & 3) * TY;

    const float* __restrict__ xp = preds + (size_t)v * VOXPV;
    const float* __restrict__ yp = trues + (size_t)v * VOXPV;

    __shared__ float s1[5 * S1F];
    __shared__ float s2[5 * S2F];
    __shared__ float wsum[4];

    // ---- slot A (always) and slot B (tid+256 < 484) padded positions ----
    const int sA  = tid;
    const int axi = sA / PY, ayi = sA % PY;
    const int gxA = min(max(ox - 3 + axi, 0), VOL - 1);
    const int gyA = min(max(oy - 3 + ayi, 0), VOL - 1);
    const float* rAx = xp + (gxA * VOL + gyA) * VOL;
    const float* rAy = yp + (gxA * VOL + gyA) * VOL;
    const int wOffA = axi * PYS + ayi;

    const int  sB   = tid + 256;
    const bool hasB = sB < NPOS;
    const int  bxi  = hasB ? sB / PY : 0;
    const int  byi  = hasB ? sB % PY : 0;
    const int gxB = min(max(ox - 3 + bxi, 0), VOL - 1);
    const int gyB = min(max(oy - 3 + byi, 0), VOL - 1);
    const float* rBx = xp + (gxB * VOL + gyB) * VOL;
    const float* rBy = yp + (gxB * VOL + gyB) * VOL;
    const int wOffB = bxi * PYS + byi;

    // roles
    const bool doY = tid < 176;             // 22 ix-rows x 8 yo-pairs
    const int  yIx = tid >> 3;
    const int  yYo = (tid & 7) * 2;
    const bool doX = tid < 128;             // 8 xo-pairs x 16 yo
    const int  xYo = tid & 15;
    const int  xXo = (tid >> 4) * 2;

    // ---- prime z windows (zc=0: taps z=-3..3 clamp -> x0,x0,x0,x0,x1,x2,x3) ----
    float4 cAx = *(const float4*)rAx;
    float4 cAy = *(const float4*)rAy;
    float4 cBx = *(const float4*)rBx;
    float4 cBy = *(const float4*)rBy;

    float wAx[7], wAy[7], wBx[7], wBy[7];
    wAx[0]=wAx[1]=wAx[2]=wAx[3]=cAx.x; wAx[4]=cAx.y; wAx[5]=cAx.z; wAx[6]=cAx.w;
    wAy[0]=wAy[1]=wAy[2]=wAy[3]=cAy.x; wAy[4]=cAy.y; wAy[5]=cAy.z; wAy[6]=cAy.w;
    wBx[0]=wBx[1]=wBx[2]=wBx[3]=cBx.x; wBx[4]=cBx.y; wBx[5]=cBx.z; wBx[6]=cBx.w;
    wBy[0]=wBy[1]=wBy[2]=wBy[3]=cBy.x; wBy[4]=cBy.y; wBy[5]=cBy.z; wBy[6]=cBy.w;

    float lsum = 0.f;

    for (int zb = 0; zb < 16; ++zb) {
        const bool more = zb < 15;
        float4 nAx = cAx, nAy = cAy, nBx = cBx, nBy = cBy;
        if (more) {
            const int zl = 4 * zb + 4;
            nAx = *(const float4*)(rAx + zl);
            nAy = *(const float4*)(rAy + zl);
            nBx = *(const float4*)(rBx + zl);
            nBy = *(const float4*)(rBy + zl);
        }
#pragma unroll
        for (int ph = 0; ph < 4; ++ph) {
            // ---- z-conv (registers) + stage1 write ----
            {
                float fA[5];
                zconv5(wAx, wAy, fA);
                s1[0*S1F + wOffA] = fA[0];
                s1[1*S1F + wOffA] = fA[1];
                s1[2*S1F + wOffA] = fA[2];
                s1[3*S1F + wOffA] = fA[3];
                s1[4*S1F + wOffA] = fA[4];
                if (hasB) {
                    float fB[5];
                    zconv5(wBx, wBy, fB);
                    s1[0*S1F + wOffB] = fB[0];
                    s1[1*S1F + wOffB] = fB[1];
                    s1[2*S1F + wOffB] = fB[2];
                    s1[3*S1F + wOffB] = fB[3];
                    s1[4*S1F + wOffB] = fB[4];
                }
            }
            __syncthreads();   // B1: stage1 ready; also fences prev x-conv reads vs s2 writes

            // ---- y-conv: pair of outputs shares 8 taps (4x ds_read_b64/field) ----
            if (doY) {
                const int base = yIx * PYS + yYo;
#pragma unroll
                for (int f = 0; f < 5; ++f) {
                    const float* p = &s1[f * S1F + base];
                    float2 q0 = *(const float2*)(p);
                    float2 q1 = *(const float2*)(p + 2);
                    float2 q2 = *(const float2*)(p + 4);
                    float2 q3 = *(const float2*)(p + 6);
                    float o0 = G0*(q0.x+q3.x) + G1*(q0.y+q2.y) + G2*(q1.x+q2.x) + G3*q1.y;
                    float o1 = G0*(q0.y+q3.y) + G1*(q1.x+q3.x) + G2*(q1.y+q2.y) + G3*q2.x;
                    s2[f*S2F + yYo*PYS + yIx]       = o0;
                    s2[f*S2F + (yYo+1)*PYS + yIx]   = o1;
                }
            }
            __syncthreads();   // B2: stage2 ready; fences y-conv s1 reads vs next s1 writes

            // ---- x-conv + SSIM: pair of outputs shares 8 taps ----
            if (doX) {
                const int base = xYo * PYS + xXo;
                float r0[5], r1[5];
#pragma unroll
                for (int f = 0; f < 5; ++f) {
                    const float* p = &s2[f * S2F + base];
                    float2 q0 = *(const float2*)(p);
                    float2 q1 = *(const float2*)(p + 2);
                    float2 q2 = *(const float2*)(p + 4);
                    float2 q3 = *(const float2*)(p + 6);
                    r0[f] = G0*(q0.x+q3.x) + G1*(q0.y+q2.y) + G2*(q1.x+q2.x) + G3*q1.y;
                    r1[f] = G0*(q0.y+q3.y) + G1*(q1.x+q3.x) + G2*(q1.y+q2.y) + G3*q2.x;
                }
                lsum += ssim_term(r0);
                lsum += ssim_term(r1);
            }

            // ---- shift windows, append z = zc+4 (clamped) ----
            {
                const float vAx = more ? f4c(nAx, ph) : cAx.w;
                const float vAy = more ? f4c(nAy, ph) : cAy.w;
                const float vBx = more ? f4c(nBx, ph) : cBx.w;
                const float vBy = more ? f4c(nBy, ph) : cBy.w;
#pragma unroll
                for (int k = 0; k < 6; ++k) {
                    wAx[k] = wAx[k+1]; wAy[k] = wAy[k+1];
                    wBx[k] = wBx[k+1]; wBy[k] = wBy[k+1];
                }
                wAx[6] = vAx; wAy[6] = vAy; wBx[6] = vBx; wBy[6] = vBy;
            }
        }
        if (more) { cAx = nAx; cAy = nAy; cBx = nBx; cBy = nBy; }
    }

    // ---- block reduction, one f64 atomic ----
#pragma unroll
    for (int off = 32; off > 0; off >>= 1)
        lsum += __shfl_down(lsum, off);
    if ((tid & 63) == 0) wsum[tid >> 6] = lsum;
    __syncthreads();
    if (tid == 0)
        atomicAdd(acc, (double)(wsum[0] + wsum[1] + wsum[2] + wsum[3]));
}

extern "C" void kernel_launch(void* const* d_in, const int* in_sizes, int n_in,
                              void* d_out, int out_size, void* d_ws, size_t ws_size,
                              hipStream_t stream) {
    const float* preds = (const float*)d_in[0];
    const float* trues = (const float*)d_in[1];
    float* out = (float*)d_out;
    double* acc = (double*)d_ws;

    hipLaunchKernelGGL(zero_acc_kernel, dim3(1), dim3(64), 0, stream, acc);

    const int nblocks = 64 * 16;   // 64 volumes x (4x4) xy-tiles, z streamed
    hipLaunchKernelGGL(ssim3d_kernel, dim3(nblocks), dim3(256), 0, stream,
                       preds, trues, acc);

    hipLaunchKernelGGL(finalize_kernel, dim3(1), dim3(64), 0, stream, acc, out);
}

// Round 4
// 154.252 us; speedup vs baseline: 2.8493x; 2.0304x over previous
//
#include <hip/hip_runtime.h>

// SSIM3D loss, 64 x 64^3 f32 volumes, separable 7-tap gaussian, edge clamp.
// Transposed structure: lanes = z (coalesced), y streamed (register windows),
// z-conv via wave shuffles, x-conv via conflict-free SoA LDS (read2st64 taps).

#define G0 0.03663285f
#define G1 0.11128074f
#define G2 0.21674532f
#define G3 0.27068219f
#define FS 896              // field stride in s1 = 14*64
#define SC1 1e-4f
#define SC2 9e-4f

__global__ void zero_acc_kernel(double* acc) { if (threadIdx.x == 0) *acc = 0.0; }

__global__ void finalize_kernel(const double* __restrict__ acc, float* __restrict__ out) {
    if (threadIdx.x == 0) out[0] = (float)(*acc * (1.0 / 16777216.0));
}

__device__ __forceinline__ float ssim_term(const float F[5]) {
    float mu1 = F[0], mu2 = F[1];
    float m11 = mu1*mu1, m22 = mu2*mu2, m12 = mu1*mu2;
    float num = (2.f*m12 + SC1) * (2.f*(F[4] - m12) + SC2);
    float den = (m11 + m22 + SC1) * ((F[2] - m11) + (F[3] - m22) + SC2) + 1e-12f;
    return 1.f - num * __builtin_amdgcn_rcpf(den);
}

__launch_bounds__(256, 2)
__global__ void ssim3d_kernel(const float* __restrict__ preds,
                              const float* __restrict__ trues,
                              double* __restrict__ acc)
{
    const int tid = threadIdx.x;
    const int z   = tid & 63;          // lane = z (contiguous dim)
    const int w   = tid >> 6;          // wave 0..3
    const int v   = blockIdx.x & 63;   // volume; all 8 x-tiles of v share XCD (bid%8==v%8)
    const int tx  = blockIdx.x >> 6;   // x-tile 0..7
    const int xo  = tx << 3;

    __shared__ float s1[2][5][FS];     // dbuf x 5 fields x 14 px x 64 z
    __shared__ float wsum[4];

    // clamped shuffle source lanes for z +/- 1..3 (replicate padding in z)
    const int izm1 = max(z-1,0), izm2 = max(z-2,0), izm3 = max(z-3,0);
    const int izp1 = min(z+1,63), izp2 = min(z+2,63), izp3 = min(z+3,63);

    // z-conv columns: px = w + 4k (w<2: k=0..3, else k=0..2) -> covers 0..13
    const float* cA[4]; const float* cB[4];
    #pragma unroll
    for (int k = 0; k < 4; ++k) {
        int px = w + 4*k; if (px > 13) px = 13;     // unused slot when w>=2,k==3
        int gx = xo - 3 + px; gx = min(max(gx, 0), 63);
        int gi = (v << 18) + (gx << 12) + z;
        cA[k] = preds + gi;  cB[k] = trues + gi;
    }

    float W0[5][7], W1[5][7];          // 7-deep y-windows for outputs x=2w, 2w+1
    float ca[4], cb[4], na[4], nb[4];
    float lsum = 0.f;

    // load plane 0, prefetch plane 1
    #pragma unroll
    for (int k = 0; k < 4; ++k) if (k < 3 || w < 2) {
        ca[k] = cA[k][0];   cb[k] = cB[k][0];
        na[k] = cA[k][64];  nb[k] = cB[k][64];
    }

    // z-conv (wave shuffles) + SoA store of 5 fields
    auto produce = [&](float* buf) {
        #pragma unroll
        for (int k = 0; k < 4; ++k) if (k < 3 || w < 2) {
            float a = ca[k], b = cb[k];
            float am1=__shfl(a,izm1), am2=__shfl(a,izm2), am3=__shfl(a,izm3);
            float ap1=__shfl(a,izp1), ap2=__shfl(a,izp2), ap3=__shfl(a,izp3);
            float bm1=__shfl(b,izm1), bm2=__shfl(b,izm2), bm3=__shfl(b,izm3);
            float bp1=__shfl(b,izp1), bp2=__shfl(b,izp2), bp3=__shfl(b,izp3);
            int o = (w + 4*k)*64 + z;
            buf[0*FS+o] = G3*a     + G2*(am1+ap1)         + G1*(am2+ap2)         + G0*(am3+ap3);
            buf[1*FS+o] = G3*b     + G2*(bm1+bp1)         + G1*(bm2+bp2)         + G0*(bm3+bp3);
            buf[2*FS+o] = G3*(a*a) + G2*(am1*am1+ap1*ap1) + G1*(am2*am2+ap2*ap2) + G0*(am3*am3+ap3*ap3);
            buf[3*FS+o] = G3*(b*b) + G2*(bm1*bm1+bp1*bp1) + G1*(bm2*bm2+bp2*bp2) + G0*(bm3*bm3+bp3*bp3);
            buf[4*FS+o] = G3*(a*b) + G2*(am1*bm1+ap1*bp1) + G1*(am2*bm2+ap2*bp2) + G0*(am3*bm3+ap3*bp3);
        }
    };

    // shift windows, x-conv (8 shared taps -> outputs 2w, 2w+1), push slot 6
    auto xconv_push = [&](const float* buf) {
        #pragma unroll
        for (int f = 0; f < 5; ++f) {
            #pragma unroll
            for (int i = 0; i < 6; ++i) { W0[f][i] = W0[f][i+1]; W1[f][i] = W1[f][i+1]; }
        }
        const float* bp = buf + (w << 7) + z;   // px = 2w, lane-consecutive (conflict-free)
        #pragma unroll
        for (int f = 0; f < 5; ++f) {
            const float* p = bp + f*FS;
            float t0=p[0],   t1=p[64],  t2=p[128], t3=p[192];
            float t4=p[256], t5=p[320], t6=p[384], t7=p[448];
            W0[f][6] = G0*(t0+t6) + G1*(t1+t5) + G2*(t2+t4) + G3*t3;
            W1[f][6] = G0*(t1+t7) + G1*(t2+t6) + G2*(t3+t5) + G3*t4;
        }
    };

    // ---- prologue: plane 0 fills window slots 3..6 (y replicate padding) ----
    produce(&s1[0][0][0]);
    __syncthreads();
    xconv_push(&s1[0][0][0]);
    #pragma unroll
    for (int f = 0; f < 5; ++f) {
        W0[f][3]=W0[f][6]; W0[f][4]=W0[f][6]; W0[f][5]=W0[f][6];
        W1[f][3]=W1[f][6]; W1[f][4]=W1[f][6]; W1[f][5]=W1[f][6];
    }
    #pragma unroll
    for (int k = 0; k < 4; ++k) { ca[k]=na[k]; cb[k]=nb[k]; }

    // ---- main stream: planes 1..63; emit y = s-3 ----
    for (int s = 1; s < 64; ++s) {
        float* buf = &s1[s & 1][0][0];
        const int off = (s < 63 ? (s + 1) : 63) << 6;   // prefetch plane s+1
        #pragma unroll
        for (int k = 0; k < 4; ++k) if (k < 3 || w < 2) { na[k]=cA[k][off]; nb[k]=cB[k][off]; }

        produce(buf);
        __syncthreads();
        xconv_push(buf);

        if (s >= 3) {
            float F0[5], F1[5];
            #pragma unroll
            for (int f = 0; f < 5; ++f) {
                F0[f] = G0*(W0[f][0]+W0[f][6]) + G1*(W0[f][1]+W0[f][5]) + G2*(W0[f][2]+W0[f][4]) + G3*W0[f][3];
                F1[f] = G0*(W1[f][0]+W1[f][6]) + G1*(W1[f][1]+W1[f][5]) + G2*(W1[f][2]+W1[f][4]) + G3*W1[f][3];
            }
            lsum += ssim_term(F0) + ssim_term(F1);
        }
        #pragma unroll
        for (int k = 0; k < 4; ++k) { ca[k]=na[k]; cb[k]=nb[k]; }
    }

    // ---- epilogue: y = 61,62,63 with clamp-folded weights (window = planes 57..63) ----
    {
        float F0[5], F1[5];
        #pragma unroll
        for (int f = 0; f < 5; ++f) {
            F0[f] = G0*W0[f][1] + G1*W0[f][2] + G2*W0[f][3] + G3*W0[f][4] + G2*W0[f][5] + (G1+G0)*W0[f][6];
            F1[f] = G0*W1[f][1] + G1*W1[f][2] + G2*W1[f][3] + G3*W1[f][4] + G2*W1[f][5] + (G1+G0)*W1[f][6];
        }
        lsum += ssim_term(F0) + ssim_term(F1);
        #pragma unroll
        for (int f = 0; f < 5; ++f) {
            F0[f] = G0*W0[f][2] + G1*W0[f][3] + G2*W0[f][4] + G3*W0[f][5] + (G2+G1+G0)*W0[f][6];
            F1[f] = G0*W1[f][2] + G1*W1[f][3] + G2*W1[f][4] + G3*W1[f][5] + (G2+G1+G0)*W1[f][6];
        }
        lsum += ssim_term(F0) + ssim_term(F1);
        #pragma unroll
        for (int f = 0; f < 5; ++f) {
            F0[f] = G0*W0[f][3] + G1*W0[f][4] + G2*W0[f][5] + (G3+G2+G1+G0)*W0[f][6];
            F1[f] = G0*W1[f][3] + G1*W1[f][4] + G2*W1[f][5] + (G3+G2+G1+G0)*W1[f][6];
        }
        lsum += ssim_term(F0) + ssim_term(F1);
    }

    // ---- block reduction, one f64 atomic ----
    #pragma unroll
    for (int off = 32; off > 0; off >>= 1)
        lsum += __shfl_down(lsum, off);
    if ((tid & 63) == 0) wsum[w] = lsum;
    __syncthreads();
    if (tid == 0)
        atomicAdd(acc, (double)(wsum[0] + wsum[1] + wsum[2] + wsum[3]));
}

extern "C" void kernel_launch(void* const* d_in, const int* in_sizes, int n_in,
                              void* d_out, int out_size, void* d_ws, size_t ws_size,
                              hipStream_t stream) {
    const float* preds = (const float*)d_in[0];
    const float* trues = (const float*)d_in[1];
    float* out = (float*)d_out;
    double* acc = (double*)d_ws;

    hipLaunchKernelGGL(zero_acc_kernel, dim3(1), dim3(64), 0, stream, acc);

    const int nblocks = 64 * 8;   // bid = tx*64 + v  (tiles of a volume share XCD)
    hipLaunchKernelGGL(ssim3d_kernel, dim3(nblocks), dim3(256), 0, stream,
                       preds, trues, acc);

    hipLaunchKernelGGL(finalize_kernel, dim3(1), dim3(64), 0, stream, acc, out);
}

// Round 5
// 117.704 us; speedup vs baseline: 3.7341x; 1.3105x over previous
//
#include <hip/hip_runtime.h>

// SSIM3D loss, 64 x 64^3 f32 volumes, separable 7-tap gaussian, edge clamp.
// lanes = z (coalesced). z-conv via per-lane clamped VMEM tap loads (L1-hit,
// vector-memory pipe). y streamed in register windows. x-conv via
// conflict-free SoA LDS (read2st64 taps). y-split x2 for 4 blocks/CU.

#define G0 0.03663285f
#define G1 0.11128074f
#define G2 0.21674532f
#define G3 0.27068219f
#define FS 896              // field stride in s1 = 14 px * 64 z
#define SC1 1e-4f
#define SC2 9e-4f

__global__ void zero_acc_kernel(double* acc) { if (threadIdx.x == 0) *acc = 0.0; }

__global__ void finalize_kernel(const double* __restrict__ acc, float* __restrict__ out) {
    if (threadIdx.x == 0) out[0] = (float)(*acc * (1.0 / 16777216.0));
}

__device__ __forceinline__ float ssim_term(const float F[5]) {
    float mu1 = F[0], mu2 = F[1];
    float m11 = mu1*mu1, m22 = mu2*mu2, m12 = mu1*mu2;
    float num = (2.f*m12 + SC1) * (2.f*(F[4] - m12) + SC2);
    float den = (m11 + m22 + SC1) * ((F[2] - m11) + (F[3] - m22) + SC2) + 1e-12f;
    return 1.f - num * __builtin_amdgcn_rcpf(den);
}

__launch_bounds__(256, 4)
__global__ void ssim3d_kernel(const float* __restrict__ preds,
                              const float* __restrict__ trues,
                              double* __restrict__ acc)
{
    const int tid = threadIdx.x;
    const int z   = tid & 63;          // lane = z (contiguous dim)
    const int w   = tid >> 6;          // wave 0..3
    const int v   = blockIdx.x & 63;   // volume; tiles of v share XCD (bid%8==v%8)
    const int r   = blockIdx.x >> 6;   // 0..15 = tx*2 + h
    const int h   = r & 1;             // y-half
    const int tx  = r >> 1;            // x-tile 0..7
    const int xo  = tx << 3;
    const int oy  = h << 5;            // 32 output y per block

    __shared__ float s1[2][5][FS];     // dbuf x 5 fields x 14 px x 64 z
    __shared__ float wsum[4];

    const float* __restrict__ xp = preds + ((size_t)v << 18);
    const float* __restrict__ yp = trues + ((size_t)v << 18);

    // per-lane clamped z-tap offsets (replicate padding), reused every plane
    int zoff[7];
#pragma unroll
    for (int j = 0; j < 7; ++j) zoff[j] = min(max(z + j - 3, 0), 63);

    // wave-uniform column bases: px = w + 4k covers 0..13 (w>=2,k==3 unused)
    int cbase[4];
#pragma unroll
    for (int k = 0; k < 4; ++k) {
        int px = w + 4*k; if (px > 13) px = 13;
        int gx = min(max(xo - 3 + px, 0), 63);
        cbase[k] = gx << 12;
    }

    float W0[5][7], W1[5][7];          // 7-deep y-windows, outputs x = 2w, 2w+1
    float lsum = 0.f;

    for (int s = 0; s < 38; ++s) {
        float* buf = &s1[s & 1][0][0];
        const int gy = min(max(oy - 3 + s, 0), 63);   // scalar (uniform)
        const int pb = gy << 6;

        // ---- z-conv: 7 VMEM taps per column (L1-hit), SoA store of 5 fields ----
#pragma unroll
        for (int k = 0; k < 4; ++k) if (k < 3 || w < 2) {
            const int cb = __builtin_amdgcn_readfirstlane(cbase[k] + pb);
            const float* pA = xp + cb;
            const float* pB = yp + cb;
            float a0=pA[zoff[0]], a1=pA[zoff[1]], a2=pA[zoff[2]], a3=pA[zoff[3]],
                  a4=pA[zoff[4]], a5=pA[zoff[5]], a6=pA[zoff[6]];
            float b0=pB[zoff[0]], b1=pB[zoff[1]], b2=pB[zoff[2]], b3=pB[zoff[3]],
                  b4=pB[zoff[4]], b5=pB[zoff[5]], b6=pB[zoff[6]];
            float m1  = G0*(a0+a6) + G1*(a1+a5) + G2*(a2+a4) + G3*a3;
            float m2  = G0*(b0+b6) + G1*(b1+b5) + G2*(b2+b4) + G3*b3;
            float e11 = G0*(a0*a0+a6*a6) + G1*(a1*a1+a5*a5) + G2*(a2*a2+a4*a4) + G3*(a3*a3);
            float e22 = G0*(b0*b0+b6*b6) + G1*(b1*b1+b5*b5) + G2*(b2*b2+b4*b4) + G3*(b3*b3);
            float e12 = G0*(a0*b0+a6*b6) + G1*(a1*b1+a5*b5) + G2*(a2*b2+a4*b4) + G3*(a3*b3);
            const int o = (w + 4*k)*64 + z;
            buf[0*FS+o] = m1;  buf[1*FS+o] = m2;
            buf[2*FS+o] = e11; buf[3*FS+o] = e22; buf[4*FS+o] = e12;
        }
        __syncthreads();

        // ---- shift y-windows; x-conv (8 shared taps -> outputs 2w, 2w+1) ----
#pragma unroll
        for (int f = 0; f < 5; ++f) {
#pragma unroll
            for (int i = 0; i < 6; ++i) { W0[f][i] = W0[f][i+1]; W1[f][i] = W1[f][i+1]; }
        }
        const float* bp = buf + (w << 7) + z;   // lane-consecutive (conflict-free)
#pragma unroll
        for (int f = 0; f < 5; ++f) {
            const float* p = bp + f*FS;
            float t0=p[0],   t1=p[64],  t2=p[128], t3=p[192];
            float t4=p[256], t5=p[320], t6=p[384], t7=p[448];
            W0[f][6] = G0*(t0+t6) + G1*(t1+t5) + G2*(t2+t4) + G3*t3;
            W1[f][6] = G0*(t1+t7) + G1*(t2+t6) + G2*(t3+t5) + G3*t4;
        }

        // ---- emit y = oy + s - 6 (window holds planes s-6..s) ----
        if (s >= 6) {
            float F0[5], F1[5];
#pragma unroll
            for (int f = 0; f < 5; ++f) {
                F0[f] = G0*(W0[f][0]+W0[f][6]) + G1*(W0[f][1]+W0[f][5]) + G2*(W0[f][2]+W0[f][4]) + G3*W0[f][3];
                F1[f] = G0*(W1[f][0]+W1[f][6]) + G1*(W1[f][1]+W1[f][5]) + G2*(W1[f][2]+W1[f][4]) + G3*W1[f][3];
            }
            lsum += ssim_term(F0) + ssim_term(F1);
        }
    }

    // ---- block reduction, one f64 atomic ----
#pragma unroll
    for (int off = 32; off > 0; off >>= 1)
        lsum += __shfl_down(lsum, off);
    if ((tid & 63) == 0) wsum[w] = lsum;
    __syncthreads();
    if (tid == 0)
        atomicAdd(acc, (double)(wsum[0] + wsum[1] + wsum[2] + wsum[3]));
}

extern "C" void kernel_launch(void* const* d_in, const int* in_sizes, int n_in,
                              void* d_out, int out_size, void* d_ws, size_t ws_size,
                              hipStream_t stream) {
    const float* preds = (const float*)d_in[0];
    const float* trues = (const float*)d_in[1];
    float* out = (float*)d_out;
    double* acc = (double*)d_ws;

    hipLaunchKernelGGL(zero_acc_kernel, dim3(1), dim3(64), 0, stream, acc);

    const int nblocks = 64 * 16;   // bid = (tx*2+h)*64 + v
    hipLaunchKernelGGL(ssim3d_kernel, dim3(nblocks), dim3(256), 0, stream,
                       preds, trues, acc);

    hipLaunchKernelGGL(finalize_kernel, dim3(1), dim3(64), 0, stream, acc, out);
}